// Round 10
// baseline (206.853 us; speedup 1.0000x reference)
//
#include <hip/hip_runtime.h>
#include <hip/hip_bf16.h>

// ---------------------------------------------------------------------------
// RRN, MFMA version, parallel scan-binned, bf16-resident e.
//   iter: e = l2norm(tanh([e;mem] @ Wc + bc))            (K=192 GEMM, MFMA)
//         per triple (unique rows): out = tanh([e_s;e_o] @ Wr[l] + br[l])
//         e[s]=l2norm(out[:128]); e[o]=l2norm(out[128:])  (layer-binned MFMA)
// subj ∪ obj are distinct rows -> in-place update race-free.
// k_class: BARRIER-FREE, LDS-FREE. Wave w owns rows [w*16,w*16+16) x ALL 8 nt
//   tiles: A-frags loaded directly from global (16 B/lane/kt), mem-part
//   unpacked from bit-packed mbits into registers, row l2norm fully in-wave.
// k_rel: wave w = nt[4w..4w+4) x 4 M-tiles, depth-2 L2 prefetch of W-frags.
// Non-temporal stores for all large cross-kernel outputs.
// ---------------------------------------------------------------------------

#define NROWS 200000
#define DD    128
#define KK    64
#define TT    50000
#define LL    8
#define BT    64
#define PADT  50560            // 64*790 >= 50000 + 8*63
#define NPASS 3125             // NROWS/64

#define NB    100              // binning blocks
#define CHB   500              // elements per binning block (NB*CHB == TT)
#define PL    8                // elements per lane (64*8 >= CHB)
#define PREPB 268              // weight-packing blocks in k_prep
#define MBB   6250             // mem bit-pack blocks (1.6M bytes / 256)

// ws layout (bytes)
#define WS_OFFS   0
#define WS_CNT    64                        // NB*LL ints = 3200
#define WS_BASE   4096                      // NB*LL ints
#define WS_BINS   8192                      // PADT*4 = 202240
#define WS_WCP    210432                    // 48 KB, 16B aligned
#define WS_WRP    (WS_WCP + 6*8*64*16)      // 259584; 1 MB
#define WS_MB     (WS_WRP + 8*8*16*64*16)   // 1308160; 1.6 MB bit-packed mem
#define WS_E16    (WS_MB + NROWS*8)         // 2908160; 51.2 MB
#define WS_NEED   (WS_E16 + (size_t)NROWS*DD*2)

typedef unsigned short u16;
typedef unsigned int   u32;
typedef unsigned long long u64;
typedef unsigned char  u8;
typedef __attribute__((ext_vector_type(8))) short bf16x8;
typedef __attribute__((ext_vector_type(4))) float f32x4;

#define SWZ(row, byte) ((byte) ^ (((row)&7)<<4))

__device__ __forceinline__ u32 bfbits(float f){
  __hip_bfloat16 h = __float2bfloat16(f);
  return (u32)*reinterpret_cast<unsigned short*>(&h);
}
__device__ __forceinline__ u32 pk(float lo, float hi){
  return bfbits(lo) | (bfbits(hi) << 16);
}
__device__ __forceinline__ float qreduce16(float ss){
  ss += __shfl_xor(ss, 1, 64);
  ss += __shfl_xor(ss, 2, 64);
  ss += __shfl_xor(ss, 4, 64);
  ss += __shfl_xor(ss, 8, 64);
  return ss;
}
__device__ __forceinline__ float fast_tanh(float x){
  float a = fabsf(x);
  float e = __expf(-2.0f*a);
  float t = (1.0f - e) * __builtin_amdgcn_rcpf(1.0f + e);
  return copysignf(t, x);
}
__device__ __forceinline__ float rnorm_scale(float ss){
  return __builtin_amdgcn_rcpf(fmaxf(__builtin_amdgcn_sqrtf(ss), 1e-12f));
}
__device__ __forceinline__ void nt_store_u16(u16* p, u16 v){
  __builtin_nontemporal_store(v, p);
}
__device__ __forceinline__ void nt_store_f32(float* p, float v){
  __builtin_nontemporal_store(v, p);
}
// 8 membership bits -> bf16x8 fragment (1.0 / 0.0)
__device__ __forceinline__ bf16x8 mem_frag(u32 byte){
  union { uint4 q; bf16x8 f; } u;
  u.q.x = ((byte&1u)  ?0x3F80u:0u) | ((byte&2u)  ?0x3F800000u:0u);
  u.q.y = ((byte&4u)  ?0x3F80u:0u) | ((byte&8u)  ?0x3F800000u:0u);
  u.q.z = ((byte&16u) ?0x3F80u:0u) | ((byte&32u) ?0x3F800000u:0u);
  u.q.w = ((byte&64u) ?0x3F80u:0u) | ((byte&128u)?0x3F800000u:0u);
  return u.f;
}

// --- prep: pack Wc/Wr into MFMA B-frag order; bin counts; mem bit-pack ------
__global__ __launch_bounds__(256) void k_prep(
    const float* __restrict__ Wc, const float* __restrict__ Wr,
    uint4* __restrict__ wcp, uint4* __restrict__ wrp,
    const int* __restrict__ layer, int* __restrict__ cnt,
    const int* __restrict__ mem, u8* __restrict__ mb8)
{
  if (blockIdx.x >= PREPB + NB){
    // mem bit-pack: thread -> 8 ints -> 1 byte
    int gid = (blockIdx.x - PREPB - NB)*256 + threadIdx.x;
    const int4* s4 = (const int4*)(mem + (size_t)gid*8);
    int4 a = s4[0], b = s4[1];
    u8 byte = (u8)((a.x!=0) | ((a.y!=0)<<1) | ((a.z!=0)<<2) | ((a.w!=0)<<3)
             | ((b.x!=0)<<4) | ((b.y!=0)<<5) | ((b.z!=0)<<6) | ((b.w!=0)<<7));
    __builtin_nontemporal_store(byte, &mb8[gid]);
    return;
  }
  if (blockIdx.x >= PREPB){
    const int bb = blockIdx.x - PREPB, lane = threadIdx.x;
    if (lane >= 64) return;
    const int lim = bb*CHB + CHB;
    int i0 = bb*CHB + lane*PL, i1 = i0 + PL; if (i1 > lim) i1 = lim;
    int c[LL] = {0,0,0,0,0,0,0,0};
    for (int i = i0; i < i1; ++i){
      int l = layer[i];
      #pragma unroll
      for (int k = 0; k < LL; ++k) c[k] += (l == k);
    }
    #pragma unroll
    for (int k = 0; k < LL; ++k){
      int v = c[k];
      v += __shfl_xor(v, 1, 64); v += __shfl_xor(v, 2, 64);
      v += __shfl_xor(v, 4, 64); v += __shfl_xor(v, 8, 64);
      v += __shfl_xor(v, 16, 64); v += __shfl_xor(v, 32, 64);
      if (lane == k) cnt[bb*LL + k] = v;
    }
    return;
  }
  int id = blockIdx.x*blockDim.x + threadIdx.x;
  if (id < 3072){                       // wcp: kt 0..5, nt 0..7
    int lane = id & 63, nt = (id >> 6) & 7, kt = id >> 9;
    int k0 = kt*32 + (lane>>4)*8, n = nt*16 + (lane&15);
    u32 p[4];
    #pragma unroll
    for (int e2 = 0; e2 < 4; ++e2)
      p[e2] = pk(Wc[(k0 + 2*e2)*DD + n], Wc[(k0 + 2*e2 + 1)*DD + n]);
    wcp[id] = make_uint4(p[0], p[1], p[2], p[3]);
  } else if (id < 3072 + 65536){        // wrp: l, kt 0..7, nt 0..15
    int id2 = id - 3072;
    int lane = id2 & 63, nt = (id2>>6) & 15, kt = (id2>>10) & 7, l = id2 >> 13;
    int k0 = kt*32 + (lane>>4)*8, n = nt*16 + (lane&15);
    const float* w = Wr + (size_t)l*65536;
    u32 p[4];
    #pragma unroll
    for (int e2 = 0; e2 < 4; ++e2)
      p[e2] = pk(w[(k0 + 2*e2)*256 + n], w[(k0 + 2*e2 + 1)*256 + n]);
    wrp[id2] = make_uint4(p[0], p[1], p[2], p[3]);
  }
}

// --- bin2: offsets + per-block bases + pad fill (1 tiny block) ---------------
__global__ __launch_bounds__(64) void k_bin2(const int* __restrict__ cnt,
                                             int* __restrict__ offs,
                                             int* __restrict__ gbase,
                                             int* __restrict__ bins)
{
  __shared__ int pre[NB][LL];
  __shared__ int tot[LL], soffs[LL+1];
  const int t = threadIdx.x;
  if (t < LL){
    int acc = 0;
    for (int bb = 0; bb < NB; ++bb){ pre[bb][t] = acc; acc += cnt[bb*LL + t]; }
    tot[t] = acc;
  }
  __syncthreads();
  if (t == 0){
    int acc = 0;
    for (int l = 0; l < LL; ++l){
      soffs[l] = acc; offs[l] = acc;
      acc += ((tot[l] + BT - 1)/BT)*BT;
    }
    soffs[LL] = acc; offs[LL] = acc;
  }
  __syncthreads();
  for (int idx = t; idx < NB*LL; idx += 64){
    int bb = idx >> 3, k = idx & 7;
    gbase[idx] = soffs[k] + pre[bb][k];
  }
  const int k = t >> 3, sub = t & 7;
  const int sz = soffs[k+1] - soffs[k];
  for (int i = tot[k] + sub; i < sz; i += 8) bins[soffs[k] + i] = -1;
}

// --- bin3: ordered scatter (NB one-wave blocks) -------------------------------
__global__ __launch_bounds__(64) void k_bin3(const int* __restrict__ layer,
                                             const int* __restrict__ gbase,
                                             int* __restrict__ bins)
{
  const int bb = blockIdx.x, lane = threadIdx.x;
  const int lim = bb*CHB + CHB;
  int i0 = bb*CHB + lane*PL, i1 = i0 + PL; if (i1 > lim) i1 = lim;
  int c[LL] = {0,0,0,0,0,0,0,0};
  for (int i = i0; i < i1; ++i){
    int l = layer[i];
    #pragma unroll
    for (int k = 0; k < LL; ++k) c[k] += (l == k);
  }
  int start[LL];
  #pragma unroll
  for (int k = 0; k < LL; ++k){
    int v = c[k];
    #pragma unroll
    for (int d = 1; d < 64; d <<= 1){
      int u = __shfl_up(v, d, 64);
      if (lane >= d) v += u;
    }
    start[k] = gbase[bb*LL + k] + v - c[k];
  }
  for (int i = i0; i < i1; ++i){
    int l = layer[i];
    #pragma unroll
    for (int k = 0; k < LL; ++k)
      if (l == k) bins[start[k]++] = i;
  }
}

// --- class update: dst = l2norm(tanh([src;mem] @ Wc + bc)) -------------------
// BARRIER-FREE, LDS-FREE. Wave w owns rows [w*16, w*16+16) x all 8 nt tiles.
// Lane (qw,colj): A-row = w*16+colj; A-frag(kt) = 16 B at row*256 + kt*64 +
// qw*16 loaded DIRECTLY from global; mem frags (kt 4,5) unpacked from mbits.
// C/D: lane holds rows w*16+qw*4+r, cols nt*16+colj -> full-row norm in-wave.
template<bool S16, bool W16, bool WF32>
__global__ __launch_bounds__(256) void k_class(
    const float* __restrict__ srcf, const u16* __restrict__ src16,
    u16* __restrict__ e16, float* __restrict__ dstf,
    const u64* __restrict__ mbits,
    const uint4* __restrict__ wcp, const float* __restrict__ bc)
{
  const int tid = threadIdx.x;
  const int lane = tid & 63, wid = tid >> 6;
  const int colj = lane & 15, qw = lane >> 4;
  const int rowbase = blockIdx.x * 64;
  const int arow = rowbase + wid*16 + colj;   // this lane's A-operand row

  // ---- issue all global loads for this lane's row ----
  bf16x8 afr[6];
  if constexpr (S16){
    const u16* rp = src16 + (size_t)arow*DD + qw*8;
    #pragma unroll
    for (int kt = 0; kt < 4; ++kt){
      uint4 q = *(const uint4*)(rp + kt*32);
      afr[kt] = *(bf16x8*)&q;
    }
  } else {
    const float* rp = srcf + (size_t)arow*DD + qw*8;
    float4 fq[8];
    #pragma unroll
    for (int kt = 0; kt < 4; ++kt){
      fq[2*kt]   = *(const float4*)(rp + kt*32);
      fq[2*kt+1] = *(const float4*)(rp + kt*32 + 4);
    }
    #pragma unroll
    for (int kt = 0; kt < 4; ++kt){
      float4 a = fq[2*kt], b = fq[2*kt+1];
      uint4 q = make_uint4(pk(a.x,a.y), pk(a.z,a.w), pk(b.x,b.y), pk(b.z,b.w));
      afr[kt] = *(bf16x8*)&q;
    }
  }
  const u64 mv = mbits[arow];
  afr[4] = mem_frag((u32)(mv >> (qw*8)) & 0xFFu);
  afr[5] = mem_frag((u32)(mv >> (32 + qw*8)) & 0xFFu);

  // bias for this lane's 8 output columns
  float b[8];
  #pragma unroll
  for (int nt = 0; nt < 8; ++nt) b[nt] = bc[nt*16 + colj];

  // ---- MFMA: 8 nt x 6 kt, B-frags streamed from L1/L2-hot wcp ----
  f32x4 acc[8];
  #pragma unroll
  for (int nt = 0; nt < 8; ++nt) acc[nt] = (f32x4){0.f,0.f,0.f,0.f};
  #pragma unroll
  for (int nt = 0; nt < 8; ++nt){
    #pragma unroll
    for (int kt = 0; kt < 6; ++kt){
      bf16x8 w = *(const bf16x8*)&wcp[(kt*8 + nt)*64 + lane];
      acc[nt] = __builtin_amdgcn_mfma_f32_16x16x32_bf16(afr[kt], w, acc[nt], 0,0,0);
    }
  }

  // ---- epilogue: tanh + FULL-ROW in-wave l2norm + nt stores ----
  #pragma unroll
  for (int r = 0; r < 4; ++r){
    float t[8], ss = 0.f;
    #pragma unroll
    for (int nt = 0; nt < 8; ++nt){
      t[nt] = fast_tanh(acc[nt][r] + b[nt]);
      ss += t[nt]*t[nt];
    }
    ss = qreduce16(ss);
    float sc = rnorm_scale(ss);
    const int orow = rowbase + wid*16 + qw*4 + r;
    #pragma unroll
    for (int nt = 0; nt < 8; ++nt){
      float v = t[nt]*sc;
      if constexpr (W16)
        nt_store_u16(&e16[(size_t)orow*DD + nt*16 + colj], (u16)bfbits(v));
      if constexpr (WF32)
        nt_store_f32(&dstf[(size_t)orow*DD + nt*16 + colj], v);
    }
  }
}

// --- relation update: 64 same-layer triples/block ----------------------------
// Wave w: ALL 4 M-tiles x nt in [4w, 4w+4). Weight frag reused 4x; depth-2
// register prefetch of weight frags hides L2 latency. Cross-wave l2norm via
// sPart (subj = waves 0,1; obj = waves 2,3). Non-temporal stores.
template<bool S16, bool W16, bool WF32>
__global__ __launch_bounds__(256) void k_rel(
    const float* __restrict__ ef32, u16* __restrict__ e16,
    float* __restrict__ dstf,
    const int* __restrict__ subj, const int* __restrict__ obj,
    const uint4* __restrict__ wrp, const float* __restrict__ br,
    const int* __restrict__ offs, const int* __restrict__ bins)
{
  __shared__ u16   sA[64*256];   // 32 KB pairs bf16, row stride 512 B, swizzled
  __shared__ float sBr[256];
  __shared__ float sPart[BT][4];
  __shared__ int   sS[BT], sO[BT];

  const int tid  = threadIdx.x;
  const int base = blockIdx.x * BT;
  if (base >= offs[LL]) return;
  int l = 0;
  while (l < LL-1 && base >= offs[l+1]) ++l;

  const int lane = tid & 63, wid = tid >> 6;
  const int colj = lane & 15, qw = lane >> 4;

  // issue first weight prefetches before the gather (rides under its latency)
  const uint4* wb = wrp + (size_t)l*8192 + lane;
  bf16x8 wf[8][4];
  #pragma unroll
  for (int n = 0; n < 4; ++n){
    wf[0][n] = *(const bf16x8*)&wb[(0*16 + wid*4 + n)*64];
    wf[1][n] = *(const bf16x8*)&wb[(1*16 + wid*4 + n)*64];
  }

  sBr[tid] = br[l*256 + tid];

  // gather pairs: 4 threads per triple, 128 B each
  const int ti = tid >> 2, q = tid & 3;
  int id = bins[base + ti];
  int rs = -1, ro = -1;
  if (id >= 0){ rs = subj[id]; ro = obj[id]; }
  if (q == 0){ sS[ti] = rs; sO[ti] = ro; }
  const int rr = (q < 2) ? rs : ro;
  if constexpr (S16){
    const u16* srcp = e16 + (size_t)rr*DD + (q & 1)*64;
    #pragma unroll
    for (int j = 0; j < 8; ++j){
      uint4 w = (id >= 0) ? ((const uint4*)srcp)[j] : make_uint4(0u,0u,0u,0u);
      *(uint4*)((char*)sA + ti*512 + SWZ(ti, q*128 + j*16)) = w;
    }
  } else {
    const float* srcp = ef32 + (size_t)rr*DD + (q & 1)*64;
    #pragma unroll
    for (int j = 0; j < 8; ++j){
      uint4 w;
      if (id >= 0){
        float4 a = ((const float4*)srcp)[2*j], b = ((const float4*)srcp)[2*j+1];
        w = make_uint4(pk(a.x,a.y), pk(a.z,a.w), pk(b.x,b.y), pk(b.z,b.w));
      } else w = make_uint4(0u,0u,0u,0u);
      *(uint4*)((char*)sA + ti*512 + SWZ(ti, q*128 + j*16)) = w;
    }
  }
  __syncthreads();

  f32x4 acc[4][4];
  #pragma unroll
  for (int m = 0; m < 4; ++m)
    #pragma unroll
    for (int n = 0; n < 4; ++n) acc[m][n] = (f32x4){0.f,0.f,0.f,0.f};

  #pragma unroll
  for (int kt = 0; kt < 8; ++kt){
    if (kt + 2 < 8){
      #pragma unroll
      for (int n = 0; n < 4; ++n)
        wf[kt+2][n] = *(const bf16x8*)&wb[((kt+2)*16 + wid*4 + n)*64];
    }
    #pragma unroll
    for (int m = 0; m < 4; ++m){
      int row = m*16 + colj;
      bf16x8 afr = *(bf16x8*)((char*)sA + row*512 + SWZ(row, kt*64 + qw*16));
      #pragma unroll
      for (int n = 0; n < 4; ++n)
        acc[m][n] = __builtin_amdgcn_mfma_f32_16x16x32_bf16(afr, wf[kt][n], acc[m][n], 0,0,0);
    }
  }

  // epilogue: tanh, partial norms (per wave: 4 nt = 64 cols), cross-wave sum
  #pragma unroll
  for (int m = 0; m < 4; ++m){
    #pragma unroll
    for (int n = 0; n < 4; ++n){
      float b = sBr[(wid*4 + n)*16 + colj];
      #pragma unroll
      for (int r = 0; r < 4; ++r)
        acc[m][n][r] = fast_tanh(acc[m][n][r] + b);
    }
    #pragma unroll
    for (int r = 0; r < 4; ++r){
      float ss = acc[m][0][r]*acc[m][0][r] + acc[m][1][r]*acc[m][1][r]
               + acc[m][2][r]*acc[m][2][r] + acc[m][3][r]*acc[m][3][r];
      ss = qreduce16(ss);
      if (colj == 0) sPart[m*16 + qw*4 + r][wid] = ss;
    }
  }
  __syncthreads();

  const int h = wid >> 1;   // 0: subj half (waves 0,1), 1: obj half (waves 2,3)
  #pragma unroll
  for (int m = 0; m < 4; ++m){
    #pragma unroll
    for (int r = 0; r < 4; ++r){
      int tri = m*16 + qw*4 + r;
      int row = h ? sO[tri] : sS[tri];
      if (row < 0) continue;
      float ss = sPart[tri][2*h] + sPart[tri][2*h + 1];
      float sc = rnorm_scale(ss);
      #pragma unroll
      for (int n = 0; n < 4; ++n){
        int cc = (wid*4 + n)*16 + colj - h*DD;
        float v = acc[m][n][r]*sc;
        if constexpr (W16)
          nt_store_u16(&e16[(size_t)row*DD + cc], (u16)bfbits(v));
        if constexpr (WF32)
          nt_store_f32(&dstf[(size_t)row*DD + cc], v);
      }
    }
  }
}

extern "C" void kernel_launch(void* const* d_in, const int* in_sizes, int n_in,
                              void* d_out, int out_size, void* d_ws, size_t ws_size,
                              hipStream_t stream) {
  (void)in_sizes; (void)n_in; (void)out_size;
  const float* emb  = (const float*)d_in[0];
  const int*   mem  = (const int*)  d_in[1];
  const int*   subj = (const int*)  d_in[2];
  const int*   obj  = (const int*)  d_in[3];
  const int*   lay  = (const int*)  d_in[4];
  const float* Wc   = (const float*)d_in[5];
  const float* bc   = (const float*)d_in[6];
  const float* Wr   = (const float*)d_in[7];
  const float* br   = (const float*)d_in[8];

  float* e   = (float*)d_out;
  char*  wsb = (char*)d_ws;
  int*   offs  = (int*)(wsb + WS_OFFS);
  int*   cnt   = (int*)(wsb + WS_CNT);
  int*   gbase = (int*)(wsb + WS_BASE);
  int*   bins  = (int*)(wsb + WS_BINS);
  uint4* wcp   = (uint4*)(wsb + WS_WCP);
  uint4* wrp   = (uint4*)(wsb + WS_WRP);
  u64*   mbits = (u64*)(wsb + WS_MB);
  u8*    mb8   = (u8*)(wsb + WS_MB);
  u16*   e16   = (u16*)(wsb + WS_E16);

  k_prep<<<PREPB + NB + MBB, 256, 0, stream>>>(Wc, Wr, wcp, wrp, lay, cnt, mem, mb8);
  k_bin2<<<1, 64, 0, stream>>>(cnt, offs, gbase, bins);
  k_bin3<<<NB, 64, 0, stream>>>(lay, gbase, bins);

  if (ws_size >= WS_NEED){
    // bf16-resident e path
    k_class<false,true,false><<<NPASS, 256, 0, stream>>>(
        emb, nullptr, e16, nullptr, mbits, wcp, bc);
    k_rel<true,true,false><<<PADT/BT, 256, 0, stream>>>(
        nullptr, e16, nullptr, subj, obj, wrp, br, offs, bins);
    k_class<true,false,true><<<NPASS, 256, 0, stream>>>(
        nullptr, e16, nullptr, e, mbits, wcp, bc);
    k_rel<false,false,true><<<PADT/BT, 256, 0, stream>>>(
        e, nullptr, e, subj, obj, wrp, br, offs, bins);
  } else {
    // f32 fallback (e lives in d_out; mbits region is tiny and always fits)
    k_class<false,false,true><<<NPASS, 256, 0, stream>>>(
        emb, nullptr, nullptr, e, mbits, wcp, bc);
    k_rel<false,false,true><<<PADT/BT, 256, 0, stream>>>(
        e, nullptr, e, subj, obj, wrp, br, offs, bins);
    k_class<false,false,true><<<NPASS, 256, 0, stream>>>(
        e, nullptr, nullptr, e, mbits, wcp, bc);
    k_rel<false,false,true><<<PADT/BT, 256, 0, stream>>>(
        e, nullptr, e, subj, obj, wrp, br, offs, bins);
  }
}

// Round 12
// 171.998 us; speedup vs baseline: 1.2026x; 1.2026x over previous
//
#include <hip/hip_runtime.h>
#include <hip/hip_bf16.h>

// ---------------------------------------------------------------------------
// RRN, MFMA version, parallel scan-binned, bf16-resident e.
//   iter: e = l2norm(tanh([e;mem] @ Wc + bc))            (K=192 GEMM, MFMA)
//         per triple (unique rows): out = tanh([e_s;e_o] @ Wr[l] + br[l])
//         e[s]=l2norm(out[:128]); e[o]=l2norm(out[128:])  (layer-binned MFMA)
// subj ∪ obj are distinct rows -> in-place update race-free.
// k_class: R9 one-shot (64-row tile/block, grid 3125), entry-issued staging
//   loads, Wc B-frags in registers, bit-packed mem.
// Outputs coalesced through an LDS transpose stage (fragment-scattered 2-4B
// stores -> flat 16B-chunk nt stores, full HBM lines) to kill the measured
// 1.5-2x write amplification. nt stores via clang ext-vector (not HIP uint4 —
// __builtin_nontemporal_store rejects HIP_vector_type).
// ---------------------------------------------------------------------------

#define NROWS 200000
#define DD    128
#define KK    64
#define TT    50000
#define LL    8
#define BT    64
#define PADT  50560            // 64*790 >= 50000 + 8*63
#define NPASS 3125             // NROWS/64

#define NB    100              // binning blocks
#define CHB   500              // elements per binning block (NB*CHB == TT)
#define PL    8                // elements per lane (64*8 >= CHB)
#define PREPB 268              // weight-packing blocks in k_prep
#define MBB   6250             // mem bit-pack blocks (1.6M bytes / 256)

// ws layout (bytes)
#define WS_OFFS   0
#define WS_CNT    64                        // NB*LL ints = 3200
#define WS_BASE   4096                      // NB*LL ints
#define WS_BINS   8192                      // PADT*4 = 202240
#define WS_WCP    210432                    // 48 KB, 16B aligned
#define WS_WRP    (WS_WCP + 6*8*64*16)      // 259584; 1 MB
#define WS_MB     (WS_WRP + 8*8*16*64*16)   // 1308160; 1.6 MB bit-packed mem
#define WS_E16    (WS_MB + NROWS*8)         // 2908160; 51.2 MB
#define WS_NEED   (WS_E16 + (size_t)NROWS*DD*2)

typedef unsigned short u16;
typedef unsigned int   u32;
typedef unsigned long long u64;
typedef unsigned char  u8;
typedef __attribute__((ext_vector_type(8))) short bf16x8;
typedef __attribute__((ext_vector_type(4))) float f32x4;
typedef __attribute__((ext_vector_type(4))) unsigned int u32x4;

#define SWZ(row, byte) ((byte) ^ (((row)&7)<<4))

__device__ __forceinline__ u32 bfbits(float f){
  __hip_bfloat16 h = __float2bfloat16(f);
  return (u32)*reinterpret_cast<unsigned short*>(&h);
}
__device__ __forceinline__ u32 pk(float lo, float hi){
  return bfbits(lo) | (bfbits(hi) << 16);
}
__device__ __forceinline__ float qreduce16(float ss){
  ss += __shfl_xor(ss, 1, 64);
  ss += __shfl_xor(ss, 2, 64);
  ss += __shfl_xor(ss, 4, 64);
  ss += __shfl_xor(ss, 8, 64);
  return ss;
}
__device__ __forceinline__ float fast_tanh(float x){
  float a = fabsf(x);
  float e = __expf(-2.0f*a);
  float t = (1.0f - e) * __builtin_amdgcn_rcpf(1.0f + e);
  return copysignf(t, x);
}
__device__ __forceinline__ float rnorm_scale(float ss){
  return __builtin_amdgcn_rcpf(fmaxf(__builtin_amdgcn_sqrtf(ss), 1e-12f));
}
__device__ __forceinline__ void nt_store_v4(void* p, u32x4 v){
  __builtin_nontemporal_store(v, (u32x4*)p);
}

// --- prep: pack Wc/Wr into MFMA B-frag order; bin counts; mem bit-pack ------
__global__ __launch_bounds__(256) void k_prep(
    const float* __restrict__ Wc, const float* __restrict__ Wr,
    uint4* __restrict__ wcp, uint4* __restrict__ wrp,
    const int* __restrict__ layer, int* __restrict__ cnt,
    const int* __restrict__ mem, u8* __restrict__ mb8)
{
  if (blockIdx.x >= PREPB + NB){
    int gid = (blockIdx.x - PREPB - NB)*256 + threadIdx.x;
    const int4* s4 = (const int4*)(mem + (size_t)gid*8);
    int4 a = s4[0], b = s4[1];
    u8 byte = (u8)((a.x!=0) | ((a.y!=0)<<1) | ((a.z!=0)<<2) | ((a.w!=0)<<3)
             | ((b.x!=0)<<4) | ((b.y!=0)<<5) | ((b.z!=0)<<6) | ((b.w!=0)<<7));
    __builtin_nontemporal_store(byte, &mb8[gid]);
    return;
  }
  if (blockIdx.x >= PREPB){
    const int bb = blockIdx.x - PREPB, lane = threadIdx.x;
    if (lane >= 64) return;
    const int lim = bb*CHB + CHB;
    int i0 = bb*CHB + lane*PL, i1 = i0 + PL; if (i1 > lim) i1 = lim;
    int c[LL] = {0,0,0,0,0,0,0,0};
    for (int i = i0; i < i1; ++i){
      int l = layer[i];
      #pragma unroll
      for (int k = 0; k < LL; ++k) c[k] += (l == k);
    }
    #pragma unroll
    for (int k = 0; k < LL; ++k){
      int v = c[k];
      v += __shfl_xor(v, 1, 64); v += __shfl_xor(v, 2, 64);
      v += __shfl_xor(v, 4, 64); v += __shfl_xor(v, 8, 64);
      v += __shfl_xor(v, 16, 64); v += __shfl_xor(v, 32, 64);
      if (lane == k) cnt[bb*LL + k] = v;
    }
    return;
  }
  int id = blockIdx.x*blockDim.x + threadIdx.x;
  if (id < 3072){                       // wcp: kt 0..5, nt 0..7
    int lane = id & 63, nt = (id >> 6) & 7, kt = id >> 9;
    int k0 = kt*32 + (lane>>4)*8, n = nt*16 + (lane&15);
    u32 p[4];
    #pragma unroll
    for (int e2 = 0; e2 < 4; ++e2)
      p[e2] = pk(Wc[(k0 + 2*e2)*DD + n], Wc[(k0 + 2*e2 + 1)*DD + n]);
    wcp[id] = make_uint4(p[0], p[1], p[2], p[3]);
  } else if (id < 3072 + 65536){        // wrp: l, kt 0..7, nt 0..15
    int id2 = id - 3072;
    int lane = id2 & 63, nt = (id2>>6) & 15, kt = (id2>>10) & 7, l = id2 >> 13;
    int k0 = kt*32 + (lane>>4)*8, n = nt*16 + (lane&15);
    const float* w = Wr + (size_t)l*65536;
    u32 p[4];
    #pragma unroll
    for (int e2 = 0; e2 < 4; ++e2)
      p[e2] = pk(w[(k0 + 2*e2)*256 + n], w[(k0 + 2*e2 + 1)*256 + n]);
    wrp[id2] = make_uint4(p[0], p[1], p[2], p[3]);
  }
}

// --- bin2: offsets + per-block bases + pad fill (1 tiny block) ---------------
__global__ __launch_bounds__(64) void k_bin2(const int* __restrict__ cnt,
                                             int* __restrict__ offs,
                                             int* __restrict__ gbase,
                                             int* __restrict__ bins)
{
  __shared__ int pre[NB][LL];
  __shared__ int tot[LL], soffs[LL+1];
  const int t = threadIdx.x;
  if (t < LL){
    int acc = 0;
    for (int bb = 0; bb < NB; ++bb){ pre[bb][t] = acc; acc += cnt[bb*LL + t]; }
    tot[t] = acc;
  }
  __syncthreads();
  if (t == 0){
    int acc = 0;
    for (int l = 0; l < LL; ++l){
      soffs[l] = acc; offs[l] = acc;
      acc += ((tot[l] + BT - 1)/BT)*BT;
    }
    soffs[LL] = acc; offs[LL] = acc;
  }
  __syncthreads();
  for (int idx = t; idx < NB*LL; idx += 64){
    int bb = idx >> 3, k = idx & 7;
    gbase[idx] = soffs[k] + pre[bb][k];
  }
  const int k = t >> 3, sub = t & 7;
  const int sz = soffs[k+1] - soffs[k];
  for (int i = tot[k] + sub; i < sz; i += 8) bins[soffs[k] + i] = -1;
}

// --- bin3: ordered scatter (NB one-wave blocks) -------------------------------
__global__ __launch_bounds__(64) void k_bin3(const int* __restrict__ layer,
                                             const int* __restrict__ gbase,
                                             int* __restrict__ bins)
{
  const int bb = blockIdx.x, lane = threadIdx.x;
  const int lim = bb*CHB + CHB;
  int i0 = bb*CHB + lane*PL, i1 = i0 + PL; if (i1 > lim) i1 = lim;
  int c[LL] = {0,0,0,0,0,0,0,0};
  for (int i = i0; i < i1; ++i){
    int l = layer[i];
    #pragma unroll
    for (int k = 0; k < LL; ++k) c[k] += (l == k);
  }
  int start[LL];
  #pragma unroll
  for (int k = 0; k < LL; ++k){
    int v = c[k];
    #pragma unroll
    for (int d = 1; d < 64; d <<= 1){
      int u = __shfl_up(v, d, 64);
      if (lane >= d) v += u;
    }
    start[k] = gbase[bb*LL + k] + v - c[k];
  }
  for (int i = i0; i < i1; ++i){
    int l = layer[i];
    #pragma unroll
    for (int k = 0; k < LL; ++k)
      if (l == k) bins[start[k]++] = i;
  }
}

// --- class update: dst = l2norm(tanh([src;mem] @ Wc + bc)) -------------------
// ONE 64-row pass per block (grid 3125). Entry-issued staging loads, Wc
// B-frags in registers, bit-packed mem. Outputs coalesced via LDS stage
// (flat [64][128] image, reuses sA region) -> flat 16B nt stores.
// W16 and WF32 are mutually exclusive (stage buffer is shared).
template<bool S16, bool W16, bool WF32>
__global__ __launch_bounds__(256) void k_class(
    const float* __restrict__ srcf, const u16* __restrict__ src16,
    u16* __restrict__ e16, float* __restrict__ dstf,
    const u64* __restrict__ mbits,
    const uint4* __restrict__ wcp, const float* __restrict__ bc)
{
  __shared__ __align__(16) char smem[32768];   // sA (24KB) / out-stage (<=32KB)
  __shared__ float sPart[64][4];
  u16* sA = (u16*)smem;

  const int tid = threadIdx.x;
  const int lane = tid & 63, wid = tid >> 6;
  const int colj = lane & 15, qw = lane >> 4;
  const int rowbase = blockIdx.x * 64;

  // --- 1) issue staging global loads into registers (T14) --------------------
  int erow[4], ecol[4];
  uint4  eA[4];
  float4 fA[4][2];
  #pragma unroll
  for (int v = 0; v < 4; ++v){
    int f = (v*256 + tid) * 8;               // flat elem idx in 64x128
    erow[v] = f >> 7; ecol[v] = f & 127;
    if constexpr (S16){
      eA[v] = *(const uint4*)(src16 + (size_t)(rowbase+erow[v])*DD + ecol[v]);
    } else {
      const float4* s4 = (const float4*)(srcf + (size_t)(rowbase+erow[v])*DD + ecol[v]);
      fA[v][0] = s4[0]; fA[v][1] = s4[1];
    }
  }
  const u64 mv = mbits[rowbase + (tid >> 2)];

  // --- 2) Wc B-fragments (L2-resident) -> registers --------------------------
  bf16x8 wf[6][2];
  #pragma unroll
  for (int kt = 0; kt < 6; ++kt)
    #pragma unroll
    for (int j = 0; j < 2; ++j)
      wf[kt][j] = *(const bf16x8*)&wcp[(kt*8 + 2*wid + j)*64 + lane];
  const float b0 = bc[(2*wid)*16 + colj];
  const float b1 = bc[(2*wid+1)*16 + colj];

  // --- 3) LDS writes ---------------------------------------------------------
  #pragma unroll
  for (int v = 0; v < 4; ++v){
    uint4 out;
    if constexpr (S16){
      out = eA[v];
    } else {
      float4 a = fA[v][0], b = fA[v][1];
      out = make_uint4(pk(a.x,a.y), pk(a.z,a.w), pk(b.x,b.y), pk(b.z,b.w));
    }
    *(uint4*)((char*)sA + erow[v]*384 + SWZ(erow[v], ecol[v]*2)) = out;
  }
  {
    const int r = tid >> 2, q = tid & 3;
    u32 s = (u32)(mv >> (q*16)) & 0xFFFFu;
    u32 p[8];
    #pragma unroll
    for (int jj = 0; jj < 8; ++jj){
      u32 lo = (s >> (2*jj))     & 1u;
      u32 hi = (s >> (2*jj + 1)) & 1u;
      p[jj] = (lo ? 0x3F80u : 0u) | (hi ? 0x3F800000u : 0u);
    }
    *(uint4*)((char*)sA + r*384 + SWZ(r, 256 + q*32))      = make_uint4(p[0],p[1],p[2],p[3]);
    *(uint4*)((char*)sA + r*384 + SWZ(r, 256 + q*32 + 16)) = make_uint4(p[4],p[5],p[6],p[7]);
  }
  __syncthreads();                                   // bar1: A staged

  // --- 4) MFMA ---------------------------------------------------------------
  f32x4 acc[4][2];
  #pragma unroll
  for (int m = 0; m < 4; ++m){
    acc[m][0] = (f32x4){0.f,0.f,0.f,0.f};
    acc[m][1] = (f32x4){0.f,0.f,0.f,0.f};
  }
  #pragma unroll
  for (int m = 0; m < 4; ++m){
    int row = m*16 + colj;
    #pragma unroll
    for (int kt = 0; kt < 6; ++kt){
      bf16x8 afr = *(bf16x8*)((char*)sA + row*384 + SWZ(row, kt*64 + qw*16));
      acc[m][0] = __builtin_amdgcn_mfma_f32_16x16x32_bf16(afr, wf[kt][0], acc[m][0], 0,0,0);
      acc[m][1] = __builtin_amdgcn_mfma_f32_16x16x32_bf16(afr, wf[kt][1], acc[m][1], 0,0,0);
    }
  }
  // --- 5) tanh + cross-wave l2norm partials ----------------------------------
  #pragma unroll
  for (int m = 0; m < 4; ++m){
    #pragma unroll
    for (int r = 0; r < 4; ++r){
      float t0 = fast_tanh(acc[m][0][r] + b0);
      float t1 = fast_tanh(acc[m][1][r] + b1);
      acc[m][0][r] = t0; acc[m][1][r] = t1;
      float ss = qreduce16(t0*t0 + t1*t1);
      if (colj == 0) sPart[m*16 + qw*4 + r][wid] = ss;
    }
  }
  __syncthreads();                                   // bar2: sPart ready, sA reads done

  // --- 6) scale -> flat LDS stage (reuses sA region) -------------------------
  #pragma unroll
  for (int m = 0; m < 4; ++m){
    #pragma unroll
    for (int r = 0; r < 4; ++r){
      int tri = m*16 + qw*4 + r;
      f32x4 p = *(f32x4*)sPart[tri];
      float sc = rnorm_scale(p[0] + p[1] + p[2] + p[3]);
      float v0 = acc[m][0][r]*sc, v1 = acc[m][1][r]*sc;
      int c0 = wid*32 + colj;
      if constexpr (W16){
        u16* so = (u16*)smem;
        so[tri*128 + c0]      = (u16)bfbits(v0);
        so[tri*128 + c0 + 16] = (u16)bfbits(v1);
      }
      if constexpr (WF32){
        float* so = (float*)smem;
        so[tri*128 + c0]      = v0;
        so[tri*128 + c0 + 16] = v1;
      }
    }
  }
  __syncthreads();                                   // bar3: stage complete

  // --- 7) flat coalesced nt stores ------------------------------------------
  if constexpr (W16){
    const u32x4* sp = (const u32x4*)smem;            // 1024 chunks (16 KB)
    u32x4* gp = (u32x4*)(e16 + (size_t)rowbase*DD);
    #pragma unroll
    for (int k = 0; k < 4; ++k)
      nt_store_v4(gp + tid + k*256, sp[tid + k*256]);
  }
  if constexpr (WF32){
    const u32x4* sp = (const u32x4*)smem;            // 2048 chunks (32 KB)
    u32x4* gp = (u32x4*)(dstf + (size_t)rowbase*DD);
    #pragma unroll
    for (int k = 0; k < 8; ++k)
      nt_store_v4(gp + tid + k*256, sp[tid + k*256]);
  }
}

// --- relation update: 64 same-layer triples/block ----------------------------
// Wave w: ALL 4 M-tiles x nt in [4w, 4w+4). Weight frag reused 4x; depth-2
// register prefetch of weight frags hides L2 latency. Cross-wave l2norm via
// sPart. W16 path: outputs coalesced via XOR-swizzled LDS stage (reuses sA),
// flat readback + per-half 16B nt stores. WF32 path: direct stores.
template<bool S16, bool W16, bool WF32>
__global__ __launch_bounds__(256) void k_rel(
    const float* __restrict__ ef32, u16* __restrict__ e16,
    float* __restrict__ dstf,
    const int* __restrict__ subj, const int* __restrict__ obj,
    const uint4* __restrict__ wrp, const float* __restrict__ br,
    const int* __restrict__ offs, const int* __restrict__ bins)
{
  __shared__ __align__(16) char smem[32768];   // sA (32KB) / out-stage (32KB)
  __shared__ float sBr[256];
  __shared__ float sPart[BT][4];
  __shared__ int   sS[BT], sO[BT];
  u16* sA = (u16*)smem;

  const int tid  = threadIdx.x;
  const int base = blockIdx.x * BT;
  if (base >= offs[LL]) return;
  int l = 0;
  while (l < LL-1 && base >= offs[l+1]) ++l;

  const int lane = tid & 63, wid = tid >> 6;
  const int colj = lane & 15, qw = lane >> 4;

  // issue first weight prefetches before the gather (rides under its latency)
  const uint4* wb = wrp + (size_t)l*8192 + lane;
  bf16x8 wf[8][4];
  #pragma unroll
  for (int n = 0; n < 4; ++n){
    wf[0][n] = *(const bf16x8*)&wb[(0*16 + wid*4 + n)*64];
    wf[1][n] = *(const bf16x8*)&wb[(1*16 + wid*4 + n)*64];
  }

  sBr[tid] = br[l*256 + tid];

  // gather pairs: 4 threads per triple, 128 B each
  const int ti = tid >> 2, q = tid & 3;
  int id = bins[base + ti];
  int rs = -1, ro = -1;
  if (id >= 0){ rs = subj[id]; ro = obj[id]; }
  if (q == 0){ sS[ti] = rs; sO[ti] = ro; }
  const int rr = (q < 2) ? rs : ro;
  if constexpr (S16){
    const u16* srcp = e16 + (size_t)rr*DD + (q & 1)*64;
    #pragma unroll
    for (int j = 0; j < 8; ++j){
      uint4 w = (id >= 0) ? ((const uint4*)srcp)[j] : make_uint4(0u,0u,0u,0u);
      *(uint4*)((char*)sA + ti*512 + SWZ(ti, q*128 + j*16)) = w;
    }
  } else {
    const float* srcp = ef32 + (size_t)rr*DD + (q & 1)*64;
    #pragma unroll
    for (int j = 0; j < 8; ++j){
      uint4 w;
      if (id >= 0){
        float4 a = ((const float4*)srcp)[2*j], b = ((const float4*)srcp)[2*j+1];
        w = make_uint4(pk(a.x,a.y), pk(a.z,a.w), pk(b.x,b.y), pk(b.z,b.w));
      } else w = make_uint4(0u,0u,0u,0u);
      *(uint4*)((char*)sA + ti*512 + SWZ(ti, q*128 + j*16)) = w;
    }
  }
  __syncthreads();

  f32x4 acc[4][4];
  #pragma unroll
  for (int m = 0; m < 4; ++m)
    #pragma unroll
    for (int n = 0; n < 4; ++n) acc[m][n] = (f32x4){0.f,0.f,0.f,0.f};

  #pragma unroll
  for (int kt = 0; kt < 8; ++kt){
    if (kt + 2 < 8){
      #pragma unroll
      for (int n = 0; n < 4; ++n)
        wf[kt+2][n] = *(const bf16x8*)&wb[((kt+2)*16 + wid*4 + n)*64];
    }
    #pragma unroll
    for (int m = 0; m < 4; ++m){
      int row = m*16 + colj;
      bf16x8 afr = *(bf16x8*)((char*)sA + row*512 + SWZ(row, kt*64 + qw*16));
      #pragma unroll
      for (int n = 0; n < 4; ++n)
        acc[m][n] = __builtin_amdgcn_mfma_f32_16x16x32_bf16(afr, wf[kt][n], acc[m][n], 0,0,0);
    }
  }

  // tanh + partial norms
  #pragma unroll
  for (int m = 0; m < 4; ++m){
    #pragma unroll
    for (int n = 0; n < 4; ++n){
      float b = sBr[(wid*4 + n)*16 + colj];
      #pragma unroll
      for (int r = 0; r < 4; ++r)
        acc[m][n][r] = fast_tanh(acc[m][n][r] + b);
    }
    #pragma unroll
    for (int r = 0; r < 4; ++r){
      float ss = acc[m][0][r]*acc[m][0][r] + acc[m][1][r]*acc[m][1][r]
               + acc[m][2][r]*acc[m][2][r] + acc[m][3][r]*acc[m][3][r];
      ss = qreduce16(ss);
      if (colj == 0) sPart[m*16 + qw*4 + r][wid] = ss;
    }
  }
  __syncthreads();   // sPart ready; sA reads done

  const int h = wid >> 1;   // 0: subj half (waves 0,1), 1: obj half (waves 2,3)
  if constexpr (W16){
    // stage: flat [tri][col 0..255], XOR-swizzled by tri (reuses sA region)
    #pragma unroll
    for (int m = 0; m < 4; ++m){
      #pragma unroll
      for (int r = 0; r < 4; ++r){
        int tri = m*16 + qw*4 + r;
        float ss = sPart[tri][2*h] + sPart[tri][2*h + 1];
        float sc = rnorm_scale(ss);
        #pragma unroll
        for (int n = 0; n < 4; ++n){
          int col = (wid*4 + n)*16 + colj;
          float v = acc[m][n][r]*sc;
          *(u16*)((char*)smem + tri*512 + ((col*2) ^ ((tri&7)<<4))) = (u16)bfbits(v);
        }
      }
    }
    __syncthreads();   // stage complete
    // flat readback: 2048 chunks of 16B; chunk c -> tri=c>>5, half=(c>>4)&1
    #pragma unroll
    for (int k = 0; k < 8; ++k){
      int c = tid + k*256;
      int tri = c >> 5, hh = (c >> 4) & 1, sub = c & 15;
      int row = hh ? sO[tri] : sS[tri];
      if (row >= 0){
        u32x4 v = *(const u32x4*)((char*)smem + ((c*16) ^ ((tri&7)<<4)));
        nt_store_v4((u32x4*)(e16 + (size_t)row*DD) + sub, v);
      }
    }
  }
  if constexpr (WF32){
    #pragma unroll
    for (int m = 0; m < 4; ++m){
      #pragma unroll
      for (int r = 0; r < 4; ++r){
        int tri = m*16 + qw*4 + r;
        int row = h ? sO[tri] : sS[tri];
        if (row < 0) continue;
        float ss = sPart[tri][2*h] + sPart[tri][2*h + 1];
        float sc = rnorm_scale(ss);
        #pragma unroll
        for (int n = 0; n < 4; ++n){
          int cc = (wid*4 + n)*16 + colj - h*DD;
          __builtin_nontemporal_store(acc[m][n][r]*sc, &dstf[(size_t)row*DD + cc]);
        }
      }
    }
  }
}

extern "C" void kernel_launch(void* const* d_in, const int* in_sizes, int n_in,
                              void* d_out, int out_size, void* d_ws, size_t ws_size,
                              hipStream_t stream) {
  (void)in_sizes; (void)n_in; (void)out_size;
  const float* emb  = (const float*)d_in[0];
  const int*   mem  = (const int*)  d_in[1];
  const int*   subj = (const int*)  d_in[2];
  const int*   obj  = (const int*)  d_in[3];
  const int*   lay  = (const int*)  d_in[4];
  const float* Wc   = (const float*)d_in[5];
  const float* bc   = (const float*)d_in[6];
  const float* Wr   = (const float*)d_in[7];
  const float* br   = (const float*)d_in[8];

  float* e   = (float*)d_out;
  char*  wsb = (char*)d_ws;
  int*   offs  = (int*)(wsb + WS_OFFS);
  int*   cnt   = (int*)(wsb + WS_CNT);
  int*   gbase = (int*)(wsb + WS_BASE);
  int*   bins  = (int*)(wsb + WS_BINS);
  uint4* wcp   = (uint4*)(wsb + WS_WCP);
  uint4* wrp   = (uint4*)(wsb + WS_WRP);
  u64*   mbits = (u64*)(wsb + WS_MB);
  u8*    mb8   = (u8*)(wsb + WS_MB);
  u16*   e16   = (u16*)(wsb + WS_E16);

  k_prep<<<PREPB + NB + MBB, 256, 0, stream>>>(Wc, Wr, wcp, wrp, lay, cnt, mem, mb8);
  k_bin2<<<1, 64, 0, stream>>>(cnt, offs, gbase, bins);
  k_bin3<<<NB, 64, 0, stream>>>(lay, gbase, bins);

  if (ws_size >= WS_NEED){
    // bf16-resident e path
    k_class<false,true,false><<<NPASS, 256, 0, stream>>>(
        emb, nullptr, e16, nullptr, mbits, wcp, bc);
    k_rel<true,true,false><<<PADT/BT, 256, 0, stream>>>(
        nullptr, e16, nullptr, subj, obj, wrp, br, offs, bins);
    k_class<true,false,true><<<NPASS, 256, 0, stream>>>(
        nullptr, e16, nullptr, e, mbits, wcp, bc);
    k_rel<false,false,true><<<PADT/BT, 256, 0, stream>>>(
        e, nullptr, e, subj, obj, wrp, br, offs, bins);
  } else {
    // f32 fallback (e lives in d_out; mbits region is tiny and always fits)
    k_class<false,false,true><<<NPASS, 256, 0, stream>>>(
        emb, nullptr, nullptr, e, mbits, wcp, bc);
    k_rel<false,false,true><<<PADT/BT, 256, 0, stream>>>(
        e, nullptr, e, subj, obj, wrp, br, offs, bins);
    k_class<false,false,true><<<NPASS, 256, 0, stream>>>(
        e, nullptr, nullptr, e, mbits, wcp, bc);
    k_rel<false,false,true><<<PADT/BT, 256, 0, stream>>>(
        e, nullptr, e, subj, obj, wrp, br, offs, bins);
  }
}